// Round 7
// baseline (259.621 us; speedup 1.0000x reference)
//
#include <hip/hip_runtime.h>
#include <cstdint>

// B=4096, T=512, I=3, H=32, C=3
#define B_TOT 4096
#define T_LEN 512
#define LOG2E 1.44269504088896340736f

typedef _Float16 f16x8 __attribute__((ext_vector_type(8)));
typedef float    f32x4 __attribute__((ext_vector_type(4)));

__device__ __forceinline__ float ex2(float v)  { return __builtin_amdgcn_exp2f(v); }
__device__ __forceinline__ float rcp_(float v) { return __builtin_amdgcn_rcpf(v); }

// Barrier-free LSTM: 1 wave per block, 2 batches per wave, 2048 blocks.
// Lane (n = lane&15, kq = lane>>4) owns state (batch n&1, hid v = 4*(n>>1)+kq).
// Recurrent matvec: 8 gate-MFMAs sharing one B fragment (B cols = batch n&1,
// duplicated x8). MFMA g rows m: gate = m&3, hid = 4g + (m>>2)
//   => quad at lane (n,kq) of MFMA g = (i,f,g,o) of (batch n&1, hid 4g+kq);
//      lane's own quad comes from MFMA (n>>1): 1-of-8 f32x4 select.
// h round-trips through LDS *within the wave* (in-order DS pipe, lgkmcnt only —
// no s_barrier anywhere in the step loop). x-term + bias via 12 fmaf/lane with
// a 4-step register prefetch pipeline from global memory.
// exp2 scales folded into weights: sigmoid rows * -log2e, tanh(g) * -2log2e.
// Merged-reciprocal gate math: 5 exp2 + 2 rcp per state per step.
__global__ __launch_bounds__(64, 2)
void lstm_nb(const float* __restrict__ x,
             const float* __restrict__ W_ih,
             const float* __restrict__ W_hh,
             const float* __restrict__ b_ih,
             const float* __restrict__ b_hh,
             const float* __restrict__ W_fc,
             const float* __restrict__ b_fc,
             float* __restrict__ out)
{
    __shared__ __align__(16) _Float16 hbuf[2][32];   // 128 B, single buffer

    const int lane = threadIdx.x;     // 1 wave per block
    const int n    = lane & 15;
    const int kq   = lane >> 4;
    const int b    = n & 1;           // my batch (0/1 within tile)
    const int v    = 4 * (n >> 1) + kq; // my hid
    const int tb   = blockIdx.x * 2;

    // ---- A fragments for the 8 gate-MFMAs (row m = n) ----
    const int   gate_m = n & 3;
    const float sm     = (gate_m == 2) ? (-2.0f * LOG2E) : (-LOG2E);
    f16x8 aW[8];
#pragma unroll
    for (int g = 0; g < 8; ++g) {
        const int R = gate_m * 32 + 4 * g + (n >> 2);
#pragma unroll
        for (int j = 0; j < 8; ++j)
            aW[g][j] = (_Float16)(sm * W_hh[R * 32 + 8 * kq + j]);
    }

    // ---- per-lane x-weights + bias for the 4 gates of my state ----
    float wx0[4], wx1[4], wx2[4], bs[4];
#pragma unroll
    for (int r = 0; r < 4; ++r) {
        const int   Rr = r * 32 + v;
        const float sr = (r == 2) ? (-2.0f * LOG2E) : (-LOG2E);
        wx0[r] = sr * W_ih[Rr * 3 + 0];
        wx1[r] = sr * W_ih[Rr * 3 + 1];
        wx2[r] = sr * W_ih[Rr * 3 + 2];
        bs[r]  = sr * (b_ih[Rr] + b_hh[Rr]);
    }

    // zero h(0)  (64 halves = 32 dwords)
    if (lane < 32) ((int*)&hbuf[0][0])[lane] = 0;

    // ---- x prefetch pipeline: 4 steps (48 B) per group, 128 groups ----
    const float4* xp = (const float4*)(x + (size_t)(tb + b) * (T_LEN * 3));
    float4 xc0 = xp[0], xc1 = xp[1], xc2 = xp[2];   // group 0

    const float K2 = -2.0f * LOG2E;
    float c = 0.0f;
    const f32x4 zero = {0.f, 0.f, 0.f, 0.f};

    const int selb0 = (n >> 1) & 1, selb1 = (n >> 1) & 2, selb2 = (n >> 1) & 4;

    for (int G = 0; G < T_LEN / 4; ++G) {
        // prefetch next group (clamped at the end; ~4-step lead)
        const int Gn = (G + 1 < T_LEN / 4) ? (G + 1) : (T_LEN / 4 - 1);
        const float4 xn0 = xp[3 * Gn + 0];
        const float4 xn1 = xp[3 * Gn + 1];
        const float4 xn2 = xp[3 * Gn + 2];

#pragma unroll
        for (int j = 0; j < 4; ++j) {
            // x for sub-step j (static unpack of the 3 float4s)
            float x0, x1, x2;
            if      (j == 0) { x0 = xc0.x; x1 = xc0.y; x2 = xc0.z; }
            else if (j == 1) { x0 = xc0.w; x1 = xc1.x; x2 = xc1.y; }
            else if (j == 2) { x0 = xc1.z; x1 = xc1.w; x2 = xc2.x; }
            else             { x0 = xc2.y; x1 = xc2.z; x2 = xc2.w; }

            // x-term + bias (independent of h -> schedules into LDS wait)
            float xq[4];
#pragma unroll
            for (int r = 0; r < 4; ++r)
                xq[r] = fmaf(wx2[r], x2, fmaf(wx1[r], x1, fmaf(wx0[r], x0, bs[r])));

            // B fragment: h[my batch][8kq..8kq+8)  (same-wave RAW via DS order)
            const f16x8 bh = *(const f16x8*)&hbuf[b][8 * kq];

            f32x4 ac[8];
#pragma unroll
            for (int g = 0; g < 8; ++g)
                ac[g] = __builtin_amdgcn_mfma_f32_16x16x32_f16(aW[g], bh, zero, 0, 0, 0);

            // 1-of-8 select (28 cndmask, depth 3)
            const f32x4 s01 = selb0 ? ac[1] : ac[0];
            const f32x4 s23 = selb0 ? ac[3] : ac[2];
            const f32x4 s45 = selb0 ? ac[5] : ac[4];
            const f32x4 s67 = selb0 ? ac[7] : ac[6];
            const f32x4 t03 = selb1 ? s23 : s01;
            const f32x4 t47 = selb1 ? s67 : s45;
            const f32x4 q   = selb2 ? t47 : t03;

            const float a0 = q[0] + xq[0];   // i (scaled)
            const float a1 = q[1] + xq[1];   // f
            const float a2 = q[2] + xq[2];   // g (2x scaled)
            const float a3 = q[3] + xq[3];   // o

            // merged-reciprocal gate math: 5 exp2 + 2 rcp
            const float ei = ex2(a0), ef = ex2(a1), eg = ex2(a2), eo = ex2(a3);
            const float pi = 1.0f + ei, pf = 1.0f + ef, pg = 1.0f + eg;
            const float mg = 1.0f - eg;
            const float p  = pi * pg;
            const float qn = mg * pf;
            const float num = fmaf(c, p, qn);
            c = num * rcp_(pf * p);

            const float ec = ex2(c * K2);
            const float po = 1.0f + eo, pc = 1.0f + ec, mc = 1.0f - ec;
            const float h  = mc * rcp_(po * pc);

            hbuf[b][v] = (_Float16)h;        // ds_write_b16 (in-order vs next read)
        }
        xc0 = xn0; xc1 = xn1; xc2 = xn2;
    }

    // ---- epilogue: out[tb+bb][cc] = b_fc[cc] + sum_k W_fc[cc][k]*h[bb][k] ----
    if (lane < 6) {
        const int bb = lane / 3, cc = lane % 3;
        float acc = b_fc[cc];
#pragma unroll
        for (int k = 0; k < 32; ++k)
            acc = fmaf(W_fc[cc * 32 + k], (float)hbuf[bb][k], acc);
        out[(tb + bb) * 3 + cc] = acc;
    }
}

extern "C" void kernel_launch(void* const* d_in, const int* in_sizes, int n_in,
                              void* d_out, int out_size, void* d_ws, size_t ws_size,
                              hipStream_t stream) {
    const float* x    = (const float*)d_in[0];
    const float* W_ih = (const float*)d_in[1];
    const float* W_hh = (const float*)d_in[2];
    const float* b_ih = (const float*)d_in[3];
    const float* b_hh = (const float*)d_in[4];
    const float* W_fc = (const float*)d_in[5];
    const float* b_fc = (const float*)d_in[6];
    float* out = (float*)d_out;

    dim3 grid(B_TOT / 2);    // 2048 one-wave blocks -> 8 independent waves/CU
    dim3 block(64);
    lstm_nb<<<grid, block, 0, stream>>>(x, W_ih, W_hh, b_ih, b_hh, W_fc, b_fc, out);
}

// Round 8
// 189.530 us; speedup vs baseline: 1.3698x; 1.3698x over previous
//
#include <hip/hip_runtime.h>
#include <cstdint>

// B=4096, T=512, I=3, H=32, C=3
#define B_TOT 4096
#define T_LEN 512
#define CHUNK 128
#define LOG2E 1.44269504088896340736f
#define HSTR  40   // hbuf inner stride in halves (80 B): 16B-aligned b128 frags

typedef _Float16 f16x8 __attribute__((ext_vector_type(8)));
typedef _Float16 f16x4 __attribute__((ext_vector_type(4)));
typedef float    f32x4 __attribute__((ext_vector_type(4)));

__device__ __forceinline__ float ex2(float v)  { return __builtin_amdgcn_exp2f(v); }
__device__ __forceinline__ float rcp_(float v) { return __builtin_amdgcn_rcpf(v); }

// R5 structure (best measured): 8-batch tile, 4 waves/block, 512 blocks ->
// 2 independent barrier groups per CU = 2 independent chains per SIMD.
// Wave w owns hids [8w, 8w+8) via TWO gate-MFMAs sharing one B fragment
// (B[k][n] = h[batch n&7][hid k]; columns 8..15 duplicate batches 0..7):
//   MFMA#1 rows m: gate = m&3, hid = 8w + (m>>2)   -> lane quad = (i,f,g,o)
//   MFMA#2 rows m: gate = m&3, hid = 8w + 4 + (m>>2)  of (batch n&7, hid ...)
// Lane (n,kq) state: (batch n&7, hid 8w + kq + (n>=8 ? 4 : 0)); 1-of-2 select.
// exp2 scale folded into A rows (sigmoid rows * -log2e, tanh(g) * -2log2e);
// bias folded into x-MFMA via K-slot 3 (xbuf pad staged as 1.0).
// R8 deltas vs R5: merged-reciprocal gate math (7 trans/state, validated in R7);
// unconditional b2 build (A-side k>=4 is zero -> B rows k>=4 are don't-cares).
__global__ __launch_bounds__(256, 2)
void lstm_b8m(const float* __restrict__ x,
              const float* __restrict__ W_ih,
              const float* __restrict__ W_hh,
              const float* __restrict__ b_ih,
              const float* __restrict__ b_hh,
              const float* __restrict__ W_fc,
              const float* __restrict__ b_fc,
              float* __restrict__ out)
{
    __shared__ __align__(16) _Float16 hbuf[2][8][HSTR];   // 1.25 KB
    __shared__ __align__(16) _Float16 xbuf[CHUNK][8][4];  // 8 KB

    const int tid  = threadIdx.x;
    const int wave = tid >> 6;        // 0..3
    const int lane = tid & 63;
    const int n    = lane & 15;
    const int kq   = lane >> 4;
    const int nb   = n & 7;           // batch column
    const int tb   = blockIdx.x * 8;

    // ---- A-fragment rows (m = n) for the two gate-MFMAs ----
    const int   gate_m = n & 3;
    const int   hl_m   = n >> 2;                       // 0..3
    const int   R1     = gate_m * 32 + 8 * wave + hl_m;
    const int   R2     = R1 + 4;
    const float sm     = (gate_m == 2) ? (-2.0f * LOG2E) : (-LOG2E);

    f16x8 aW1, aW2;
#pragma unroll
    for (int j = 0; j < 8; ++j) {
        aW1[j] = (_Float16)(sm * W_hh[R1 * 32 + 8 * kq + j]);
        aW2[j] = (_Float16)(sm * W_hh[R2 * 32 + 8 * kq + j]);
    }
    f16x8 a21 = {}, a22 = {};         // x-weights + bias (kq==0 lanes carry K 0..3)
    if (kq == 0) {
        a21[0] = (_Float16)(sm * W_ih[R1 * 3 + 0]);
        a21[1] = (_Float16)(sm * W_ih[R1 * 3 + 1]);
        a21[2] = (_Float16)(sm * W_ih[R1 * 3 + 2]);
        a21[3] = (_Float16)(sm * (b_ih[R1] + b_hh[R1]));
        a22[0] = (_Float16)(sm * W_ih[R2 * 3 + 0]);
        a22[1] = (_Float16)(sm * W_ih[R2 * 3 + 1]);
        a22[2] = (_Float16)(sm * W_ih[R2 * 3 + 2]);
        a22[3] = (_Float16)(sm * (b_ih[R2] + b_hh[R2]));
    }

    // my state: (batch nb, hid_s)
    const int hid_s = 8 * wave + kq + ((n >> 3) ? 4 : 0);

    // zero h(0) buffer (hbuf[0] = 8*HSTR halves = 160 ints)
    if (tid < 160) ((int*)&hbuf[0][0][0])[tid] = 0;

    const float K2 = -2.0f * LOG2E;
    float c = 0.0f;
    const f32x4 z = {0.f, 0.f, 0.f, 0.f};
    f32x4 accx1, accx2;   // prefetched x-contribution (incl. bias)

    for (int tc = 0; tc < T_LEN; tc += CHUNK) {
        // ---- stage x chunk as fp16, pad slot = 1.0 (bias trick) ----
#pragma unroll
        for (int s = 0; s < 4; ++s) {
            const int idx = tid + s * 256;          // 1024 (t,m) pairs
            const int tl = idx >> 3, m = idx & 7;
            const float* xp = x + ((size_t)(tb + m) * T_LEN + (tc + tl)) * 3;
            f16x4 v;
            v[0] = (_Float16)xp[0]; v[1] = (_Float16)xp[1];
            v[2] = (_Float16)xp[2]; v[3] = (_Float16)1.0f;
            *(f16x4*)&xbuf[tl][m][0] = v;
        }
        __syncthreads();

        {   // accx for first step of chunk (b2 rows k>=4 are don't-cares)
            const f16x4 xv = *(const f16x4*)&xbuf[0][nb][0];
            const f16x8 b2 = __builtin_shufflevector(xv, xv, 0, 1, 2, 3, 0, 1, 2, 3);
            accx1 = __builtin_amdgcn_mfma_f32_16x16x32_f16(a21, b2, z, 0, 0, 0);
            accx2 = __builtin_amdgcn_mfma_f32_16x16x32_f16(a22, b2, z, 0, 0, 0);
        }

#pragma unroll 2
        for (int tt = 0; tt < CHUNK; ++tt) {
            const int p = tt & 1;   // tc is a multiple of CHUNK (even)

            // post-barrier critical path: read h -> 2 MFMA -> select -> trans -> write
            const f16x8 bh  = *(const f16x8*)&hbuf[p][nb][8 * kq];
            const f32x4 ac1 = __builtin_amdgcn_mfma_f32_16x16x32_f16(aW1, bh, accx1, 0, 0, 0);
            const f32x4 ac2 = __builtin_amdgcn_mfma_f32_16x16x32_f16(aW2, bh, accx2, 0, 0, 0);

            const bool hi = (n >> 3) != 0;
            const float a0 = hi ? ac2[0] : ac1[0];   // i' (scaled pre-act)
            const float a1 = hi ? ac2[1] : ac1[1];   // f'
            const float a2 = hi ? ac2[2] : ac1[2];   // g' (2x scale)
            const float a3 = hi ? ac2[3] : ac1[3];   // o'

            // merged-reciprocal gate math: 5 exp2 + 2 rcp per state
            const float ei = ex2(a0), ef = ex2(a1), eg = ex2(a2), eo = ex2(a3);
            const float pi = 1.0f + ei, pf = 1.0f + ef, pg = 1.0f + eg;
            const float mg = 1.0f - eg;
            const float pp  = pi * pg;
            const float qn  = mg * pf;
            const float num = fmaf(c, pp, qn);
            c = num * rcp_(pf * pp);

            const float ec = ex2(c * K2);
            const float po = 1.0f + eo, pc = 1.0f + ec, mc = 1.0f - ec;
            const float h  = mc * rcp_(po * pc);

            hbuf[p ^ 1][nb][hid_s] = (_Float16)h;

            // prefetch next step's x-part (independent of h) before the barrier
            const int ttn = (tt + 1 < CHUNK) ? (tt + 1) : 0;   // boundary: dummy
            const f16x4 xv = *(const f16x4*)&xbuf[ttn][nb][0];
            const f16x8 b2 = __builtin_shufflevector(xv, xv, 0, 1, 2, 3, 0, 1, 2, 3);
            accx1 = __builtin_amdgcn_mfma_f32_16x16x32_f16(a21, b2, z, 0, 0, 0);
            accx2 = __builtin_amdgcn_mfma_f32_16x16x32_f16(a22, b2, z, 0, 0, 0);

            __syncthreads();
        }
    }

    // ---- epilogue: out[tb+m][cc] = b_fc[cc] + sum_k W_fc[cc][k]*h[m][k] ----
    // final h (t=512) is in hbuf[0]; last loop barrier ordered it.
    if (tid < 24) {
        const int m = tid / 3, cc = tid % 3;
        float acc = b_fc[cc];
#pragma unroll
        for (int k = 0; k < 32; ++k)
            acc = fmaf(W_fc[cc * 32 + k], (float)hbuf[0][m][k], acc);
        out[(tb + m) * 3 + cc] = acc;
    }
}

extern "C" void kernel_launch(void* const* d_in, const int* in_sizes, int n_in,
                              void* d_out, int out_size, void* d_ws, size_t ws_size,
                              hipStream_t stream) {
    const float* x    = (const float*)d_in[0];
    const float* W_ih = (const float*)d_in[1];
    const float* W_hh = (const float*)d_in[2];
    const float* b_ih = (const float*)d_in[3];
    const float* b_hh = (const float*)d_in[4];
    const float* W_fc = (const float*)d_in[5];
    const float* b_fc = (const float*)d_in[6];
    float* out = (float*)d_out;

    dim3 grid(B_TOT / 8);    // 512 blocks -> 2 independent barrier groups per CU
    dim3 block(256);         // 4 waves, 8 hids/wave
    lstm_b8m<<<grid, block, 0, stream>>>(x, W_ih, W_hh, b_ih, b_hh, W_fc, b_fc, out);
}